// Round 2
// baseline (219.017 us; speedup 1.0000x reference)
//
#include <hip/hip_runtime.h>

// y = W @ x + bias, W in COO (rows sorted), fp32.
// R7: persistent grid-stride blocks + span-level software pipeline.
// R6 post-mortem: bigger CHUNK in a monolithic phase doesn't create MLP
// (compiler clamps liveness, VGPR stayed 40) and costs occupancy. The
// real structure: blocks averaged 25us residency for ~3us of work — each
// block is a cold serial chain stream->gather->acc->epilogue->exit.
// R7 overlaps span s+1's streaming loads (and row bounds) under span s's
// gather+accumulate+epilogue, with double-buffered LDS acc (2 lgkm-only
// barriers/iter; prefetched vmem stays in flight across them).

constexpr int       CHUNK = 8;                        // nnz per thread
constexpr int       BLOCK = 256;
constexpr long long SPAN  = (long long)BLOCK * CHUNK; // 2048 nnz per span
constexpr int       RMAX  = 768;                      // LDS acc slots per buf
constexpr int       GRID_CAP = 2048;                  // 8 blocks/CU * 256 CU

typedef float vfloat4 __attribute__((ext_vector_type(4)));
typedef int   vint4   __attribute__((ext_vector_type(4)));

__global__ void init_y_bias(const float* __restrict__ bias,
                            float* __restrict__ y, int n) {
    int i = blockIdx.x * blockDim.x + threadIdx.x;
    if (i < n) y[i] = bias[i];
}

__device__ __forceinline__ void lds_add(float* p, float v) {
    // workgroup-scope relaxed fp add -> ds_add_f32 (no TCC involvement)
    __hip_atomic_fetch_add(p, v, __ATOMIC_RELAXED, __HIP_MEMORY_SCOPE_WORKGROUP);
}

// Barrier waiting ONLY on LDS/SMEM (lgkmcnt); global loads stay in flight.
// All cross-phase dependencies here are LDS ops (ds_write/ds_add/ds_read),
// which the "memory" clobber orders correctly.
__device__ __forceinline__ void barrier_lds_only() {
    asm volatile("s_waitcnt lgkmcnt(0)" ::: "memory");
    __builtin_amdgcn_s_barrier();
}

__device__ __forceinline__ void load_span_stream(
        const float* __restrict__ vals, const int* __restrict__ rows,
        const int* __restrict__ cols, long long i0,
        float v[CHUNK], int r[CHUNK], int c[CHUNK]) {
    const vint4*   c4 = reinterpret_cast<const vint4*>(cols + i0);
    const vfloat4* v4 = reinterpret_cast<const vfloat4*>(vals + i0);
    const vint4*   r4 = reinterpret_cast<const vint4*>(rows + i0);
    #pragma unroll
    for (int q = 0; q < CHUNK / 4; ++q) {
        vint4   cc = __builtin_nontemporal_load(c4 + q);
        vfloat4 vv = __builtin_nontemporal_load(v4 + q);
        vint4   rr = __builtin_nontemporal_load(r4 + q);
        #pragma unroll
        for (int j = 0; j < 4; ++j) {
            c[4*q+j] = cc[j]; v[4*q+j] = vv[j]; r[4*q+j] = rr[j];
        }
    }
}

__global__ __launch_bounds__(BLOCK) void spmv_coo_lds(
        const float* __restrict__ vals,
        const float* __restrict__ x,
        const int*   __restrict__ rows,
        const int*   __restrict__ cols,
        const float* __restrict__ bias,
        float*       __restrict__ y,
        long long nnz) {
    __shared__ float acc[2][RMAX];
    const int tid = threadIdx.x;
    const long long nspans = (nnz + SPAN - 1) / SPAN;
    long long s = blockIdx.x;
    if (s >= nspans) return;
    const long long G = gridDim.x;

    float v[CHUNK]; int r[CHUNK]; int c[CHUNK];
    float vn[CHUNK]; int rn[CHUNK]; int cn[CHUNK];

    // ---- prologue: current span streaming + bounds; zero buf 0 fully ----
    long long b0   = s * SPAN;
    long long bend = (b0 + SPAN < nnz) ? (b0 + SPAN) : nnz;
    bool      full = (b0 + SPAN) <= nnz;           // block-uniform
    if (full) load_span_stream(vals, rows, cols, b0 + (long long)tid * CHUNK,
                               v, r, c);
    int r0 = rows[b0];
    int rl = rows[bend - 1];
    #pragma unroll
    for (int i = tid; i < RMAX; i += BLOCK) acc[0][i] = 0.f;
    int range = rl - r0 + 1;
    int p = 0;
    barrier_lds_only();                            // zeros visible; vmem in flight

    while (true) {
        const long long i0 = b0 + (long long)tid * CHUNK;
        const long long snext = s + G;
        const bool have_next = snext < nspans;     // block-uniform

        // ---- phase A: gathers for s; prefetch s+1; accumulate s ----
        float g[CHUNK];
        if (full) {
            #pragma unroll
            for (int k = 0; k < CHUNK; ++k) g[k] = x[c[k]];
        }

        long long nb0 = 0, nbend = 0;
        bool nfull = false;
        int r0n = 0, rln = 0;
        if (have_next) {
            nb0   = snext * SPAN;
            nbend = (nb0 + SPAN < nnz) ? (nb0 + SPAN) : nnz;
            nfull = (nb0 + SPAN) <= nnz;
            if (nfull) load_span_stream(vals, rows, cols,
                                        nb0 + (long long)tid * CHUNK,
                                        vn, rn, cn);
            r0n = rows[nb0];
            rln = rows[nbend - 1];
        }

        if (range <= RMAX) {
            if (full) {
                int   cur = r[0];
                float sum = v[0] * g[0];
                #pragma unroll
                for (int k = 1; k < CHUNK; ++k) {
                    if (r[k] != cur) {             // row boundary: flush run
                        lds_add(&acc[p][cur - r0], sum);
                        cur = r[k];
                        sum = 0.f;
                    }
                    sum += v[k] * g[k];
                }
                lds_add(&acc[p][cur - r0], sum);
            } else if (i0 < bend) {
                // scalar partial-span path (only the globally-last span)
                int   cur = rows[i0];
                float sum = 0.f;
                long long kend = (i0 + CHUNK < bend) ? (i0 + CHUNK) : bend;
                for (long long k = i0; k < kend; ++k) {
                    int rk = rows[k];
                    if (rk != cur) { lds_add(&acc[p][cur - r0], sum); sum = 0.f; cur = rk; }
                    sum += vals[k] * x[cols[k]];
                }
                lds_add(&acc[p][cur - r0], sum);
            }
        } else {
            // pathological row-gap fallback: per-thread global atomics
            if (i0 < bend) {
                if (full) {
                    int   cur = r[0];
                    float sum = v[0] * g[0];
                    #pragma unroll
                    for (int k = 1; k < CHUNK; ++k) {
                        if (r[k] != cur) { atomicAdd(&y[cur], sum); sum = 0.f; cur = r[k]; }
                        sum += v[k] * g[k];
                    }
                    atomicAdd(&y[cur], sum);
                } else {
                    int   cur = rows[i0];
                    float sum = 0.f;
                    long long kend = (i0 + CHUNK < bend) ? (i0 + CHUNK) : bend;
                    for (long long k = i0; k < kend; ++k) {
                        int rk = rows[k];
                        if (rk != cur) { atomicAdd(&y[cur], sum); sum = 0.f; cur = rk; }
                        sum += vals[k] * x[cols[k]];
                    }
                    atomicAdd(&y[cur], sum);
                }
            }
        }
        barrier_lds_only();                        // acc[p] complete

        // ---- phase E: epilogue for span s; zero buf p^1 for span s+1 ----
        if (range <= RMAX) {
            for (int i = tid; i < range; i += BLOCK) {
                int   rr = r0 + i;
                float a  = acc[p][i];
                if (rr == r0 || rr == rl) {
                    if (a != 0.f) atomicAdd(&y[rr], a);  // may span block boundary
                } else {
                    y[rr] = bias[rr] + a;                // plain coalesced store
                }
            }
        }

        if (!have_next) break;

        int rangen = rln - r0n + 1;
        int zrn = (rangen < RMAX) ? rangen : RMAX;
        for (int i = tid; i < zrn; i += BLOCK) acc[p ^ 1][i] = 0.f;
        barrier_lds_only();                        // zeros visible; prefetch in flight

        // ---- rotate pipeline state ----
        s = snext; b0 = nb0; bend = nbend; full = nfull;
        r0 = r0n; rl = rln; range = rangen; p ^= 1;
        #pragma unroll
        for (int k = 0; k < CHUNK; ++k) { v[k] = vn[k]; r[k] = rn[k]; c[k] = cn[k]; }
    }
}

extern "C" void kernel_launch(void* const* d_in, const int* in_sizes, int n_in,
                              void* d_out, int out_size, void* d_ws, size_t ws_size,
                              hipStream_t stream) {
    const float* vals = (const float*)d_in[0];
    const float* x    = (const float*)d_in[1];
    const float* bias = (const float*)d_in[2];
    const int*   rows = (const int*)d_in[3];
    const int*   cols = (const int*)d_in[4];
    float* y = (float*)d_out;

    const long long nnz = in_sizes[0];
    const int n_rows    = in_sizes[2];   // len(bias) == n_rows

    // 1) y = bias (covers empty gap-rows + rows receiving boundary atomics)
    {
        int threads = 256;
        int blocks  = (n_rows + threads - 1) / threads;
        init_y_bias<<<blocks, threads, 0, stream>>>(bias, y, n_rows);
    }

    // 2) persistent pipelined block-local LDS-accumulated COO reduce
    {
        long long nspans = (nnz + SPAN - 1) / SPAN;
        long long blocks = (nspans < (long long)GRID_CAP) ? nspans : (long long)GRID_CAP;
        spmv_coo_lds<<<(int)blocks, BLOCK, 0, stream>>>(
            vals, x, rows, cols, bias, y, nnz);
    }
}

// Round 3
// 204.022 us; speedup vs baseline: 1.0735x; 1.0735x over previous
//
#include <hip/hip_runtime.h>

// y = W @ x + bias, W in COO (rows sorted), fp32.
// R8: R5 structure (the best measured: 77.9us) with memory-path flags only.
// (1) Streaming loads (vals/rows/cols) are PLAIN loads now, not nontemporal:
//     all 155MB of problem data fits the 256MB L3, so letting streams
//     allocate makes subsequent dispatches L3-hit (FETCH_SIZE was 81.5MB of
//     HBM re-fetch caused by the evict-first nt flag).
// (2) x-gathers use agent-scope relaxed atomic loads -> sc-flagged
//     global_load that bypasses the L1 allocate path. x (800KB) misses L1
//     (~4% hit) on every access; the L1 miss/MSHR path was the suspected
//     gather-throughput limiter. x stays L2-resident per XCD (800KB < 4MB).
// R6/R7 post-mortem: structural rewrites (lgkm-only barriers, CHUNK=16,
// persistent pipelined blocks) all regressed; with 8 blocks/CU co-resident
// the block phases already overlap. Keep R5's simple shape.

constexpr int       CHUNK = 8;                        // nnz per thread
constexpr int       BLOCK = 256;
constexpr long long SPAN  = (long long)BLOCK * CHUNK; // 2048 nnz per block
constexpr int       RMAX  = 768;                      // LDS acc slots (3 KB)

typedef float vfloat4 __attribute__((ext_vector_type(4)));
typedef int   vint4   __attribute__((ext_vector_type(4)));

__global__ void init_y_bias(const float* __restrict__ bias,
                            float* __restrict__ y, int n) {
    int i = blockIdx.x * blockDim.x + threadIdx.x;
    if (i < n) y[i] = bias[i];
}

__device__ __forceinline__ void lds_add(float* p, float v) {
    // workgroup-scope relaxed fp add -> ds_add_f32 (no TCC involvement)
    __hip_atomic_fetch_add(p, v, __ATOMIC_RELAXED, __HIP_MEMORY_SCOPE_WORKGROUP);
}

// L2-direct gather: agent-scope relaxed load bypasses L1 allocation
// (x misses L1 anyway; frees the L1 miss/MSHR path).
__device__ __forceinline__ float load_x(const float* p) {
    return __hip_atomic_load(p, __ATOMIC_RELAXED, __HIP_MEMORY_SCOPE_AGENT);
}

__global__ __launch_bounds__(BLOCK) void spmv_coo_lds(
        const float* __restrict__ vals,
        const float* __restrict__ x,
        const int*   __restrict__ rows,
        const int*   __restrict__ cols,
        const float* __restrict__ bias,
        float*       __restrict__ y,
        long long nnz) {
    __shared__ float acc[RMAX];
    const int tid = threadIdx.x;
    const long long b0 = (long long)blockIdx.x * SPAN;
    if (b0 >= nnz) return;                       // whole block exits uniformly
    const long long bend = (b0 + SPAN < nnz) ? (b0 + SPAN) : nnz;
    const bool full = (b0 + SPAN) <= nnz;        // block-uniform

    // ---- issue streaming loads FIRST: latency overlaps the prologue ----
    float v[CHUNK]; int r[CHUNK]; int c[CHUNK];
    const long long i0 = b0 + (long long)tid * CHUNK;
    if (full) {
        const vfloat4* v4 = reinterpret_cast<const vfloat4*>(vals + i0);
        const vint4*   r4 = reinterpret_cast<const vint4*>(rows + i0);
        const vint4*   c4 = reinterpret_cast<const vint4*>(cols + i0);
        #pragma unroll
        for (int q = 0; q < CHUNK / 4; ++q) {
            vfloat4 vv = v4[q];                   // plain: L2/L3-allocating
            vint4   rr = r4[q];
            vint4   cc = c4[q];
            #pragma unroll
            for (int j = 0; j < 4; ++j) {
                v[4*q+j] = vv[j];
                r[4*q+j] = rr[j];
                c[4*q+j] = cc[j];
            }
        }
    }

    // ---- prologue: fixed-size zero (independent of row-range loads) ----
    #pragma unroll
    for (int i = tid; i < RMAX; i += BLOCK) acc[i] = 0.f;
    const int r0    = rows[b0];
    const int rl    = rows[bend - 1];
    const int range = rl - r0 + 1;
    __syncthreads();

    if (range <= RMAX) {
        if (full) {
            // gathers up front (MLP); x stays L2-resident per XCD
            float g[CHUNK];
            #pragma unroll
            for (int k = 0; k < CHUNK; ++k) g[k] = load_x(&x[c[k]]);

            int   cur = r[0];
            float sum = v[0] * g[0];
            #pragma unroll
            for (int k = 1; k < CHUNK; ++k) {
                if (r[k] != cur) {               // row boundary: flush run
                    lds_add(&acc[cur - r0], sum);
                    cur = r[k];
                    sum = 0.f;
                }
                sum += v[k] * g[k];
            }
            lds_add(&acc[cur - r0], sum);
        } else if (i0 < bend) {
            // scalar partial-block path
            int   cur = rows[i0];
            float sum = 0.f;
            long long kend = (i0 + CHUNK < bend) ? (i0 + CHUNK) : bend;
            for (long long k = i0; k < kend; ++k) {
                int rk = rows[k];
                if (rk != cur) { lds_add(&acc[cur - r0], sum); sum = 0.f; cur = rk; }
                sum += vals[k] * load_x(&x[cols[k]]);
            }
            lds_add(&acc[cur - r0], sum);
        }
        __syncthreads();

        // ---- coalesced epilogue: interior rows exclusively owned ----
        for (int i = tid; i < range; i += BLOCK) {
            int   rr = r0 + i;
            float a  = acc[i];
            if (rr == r0 || rr == rl) {
                if (a != 0.f) atomicAdd(&y[rr], a);  // may span block boundary
            } else {
                y[rr] = bias[rr] + a;                // plain coalesced store
            }
        }
    } else {
        // pathological row-gap fallback: per-thread global atomics
        if (i0 < bend) {
            if (full) {
                float g[CHUNK];
                #pragma unroll
                for (int k = 0; k < CHUNK; ++k) g[k] = load_x(&x[c[k]]);
                int   cur = r[0];
                float sum = v[0] * g[0];
                #pragma unroll
                for (int k = 1; k < CHUNK; ++k) {
                    if (r[k] != cur) { atomicAdd(&y[cur], sum); sum = 0.f; cur = r[k]; }
                    sum += v[k] * g[k];
                }
                atomicAdd(&y[cur], sum);
            } else {
                int   cur = rows[i0];
                float sum = 0.f;
                long long kend = (i0 + CHUNK < bend) ? (i0 + CHUNK) : bend;
                for (long long k = i0; k < kend; ++k) {
                    int rk = rows[k];
                    if (rk != cur) { atomicAdd(&y[cur], sum); sum = 0.f; cur = rk; }
                    sum += vals[k] * load_x(&x[cols[k]]);
                }
                atomicAdd(&y[cur], sum);
            }
        }
    }
}

extern "C" void kernel_launch(void* const* d_in, const int* in_sizes, int n_in,
                              void* d_out, int out_size, void* d_ws, size_t ws_size,
                              hipStream_t stream) {
    const float* vals = (const float*)d_in[0];
    const float* x    = (const float*)d_in[1];
    const float* bias = (const float*)d_in[2];
    const int*   rows = (const int*)d_in[3];
    const int*   cols = (const int*)d_in[4];
    float* y = (float*)d_out;

    const long long nnz = in_sizes[0];
    const int n_rows    = in_sizes[2];   // len(bias) == n_rows

    // 1) y = bias (covers empty gap-rows + rows receiving boundary atomics)
    {
        int threads = 256;
        int blocks  = (n_rows + threads - 1) / threads;
        init_y_bias<<<blocks, threads, 0, stream>>>(bias, y, n_rows);
    }

    // 2) block-local LDS-accumulated COO reduce
    {
        long long blocks = (nnz + SPAN - 1) / SPAN;
        spmv_coo_lds<<<(int)blocks, BLOCK, 0, stream>>>(
            vals, x, rows, cols, bias, y, nnz);
    }
}